// Round 2
// 407.452 us; speedup vs baseline: 1.0420x; 1.0420x over previous
//
#include <hip/hip_runtime.h>
#include <hip/hip_bf16.h>

#define FDIM 128

typedef __attribute__((ext_vector_type(8))) short short8;
typedef __attribute__((ext_vector_type(4))) float f32x4;
typedef __attribute__((ext_vector_type(4))) float floatx4;
typedef __attribute__((ext_vector_type(4))) unsigned int uintx4;

__device__ inline float bflo(unsigned u) { return __uint_as_float(u << 16); }
__device__ inline float bfhi(unsigned u) { return __uint_as_float(u & 0xffff0000u); }
__device__ inline unsigned short f2bf(float f) {
    unsigned u = __float_as_uint(f);
    u += 0x7fffu + ((u >> 16) & 1u);   // RNE
    return (unsigned short)(u >> 16);
}
__device__ inline unsigned pack2(float a, float b) {
    return (unsigned)f2bf(a) | ((unsigned)f2bf(b) << 16);
}

// ---------------- degree count ----------------
__global__ __launch_bounds__(256) void deg_kernel(const int* __restrict__ dst, int* __restrict__ cnt, int E) {
    int e = blockIdx.x * 256 + threadIdx.x;
    if (e < E) atomicAdd(&cnt[dst[e]], 1);
}

// ---------------- scan phase A ----------------
__global__ __launch_bounds__(256) void scan_partial(const int* __restrict__ cnt, int* __restrict__ bsum, int n) {
    __shared__ int sdata[256];
    int b = blockIdx.x, t = threadIdx.x;
    int base = b * 1024;
    int s = 0;
    for (int i = 0; i < 4; i++) {
        int idx = base + t * 4 + i;
        if (idx < n) s += cnt[idx];
    }
    sdata[t] = s;
    __syncthreads();
    for (int off = 128; off > 0; off >>= 1) {
        if (t < off) sdata[t] += sdata[t + off];
        __syncthreads();
    }
    if (t == 0) bsum[b] = sdata[0];
}

// ---------------- scan phase B: exclusive scan of block sums (nb <= 256) ----------------
__global__ __launch_bounds__(256) void scan_sums(int* __restrict__ bsum, int nb) {
    __shared__ int sdata[256];
    int t = threadIdx.x;
    int v = (t < nb) ? bsum[t] : 0;
    sdata[t] = v;
    __syncthreads();
    for (int off = 1; off < 256; off <<= 1) {
        int u = (t >= off) ? sdata[t - off] : 0;
        __syncthreads();
        sdata[t] += u;
        __syncthreads();
    }
    if (t < nb) bsum[t] = sdata[t] - v;
}

// ---------------- scan phase C (+ fused dinv) ----------------
__global__ __launch_bounds__(256) void scan_final(const int* __restrict__ cnt, const int* __restrict__ bsum,
                                                  int* __restrict__ rowptr, float* __restrict__ dinv,
                                                  int n, int E) {
    __shared__ int sdata[256];
    int b = blockIdx.x, t = threadIdx.x;
    int base = b * 1024;
    int loc[4], vv[4];
    int s = 0;
    for (int i = 0; i < 4; i++) {
        int idx = base + t * 4 + i;
        int v = (idx < n) ? cnt[idx] : 0;
        vv[i] = v;
        loc[i] = s;
        s += v;
    }
    sdata[t] = s;
    __syncthreads();
    for (int off = 1; off < 256; off <<= 1) {
        int v = (t >= off) ? sdata[t - off] : 0;
        __syncthreads();
        sdata[t] += v;
        __syncthreads();
    }
    int texc = sdata[t] - s;
    int boff = bsum[b];
    for (int i = 0; i < 4; i++) {
        int idx = base + t * 4 + i;
        if (idx < n) {
            rowptr[idx] = boff + texc + loc[i];
            dinv[idx] = rsqrtf((float)(vv[i] + 1));
        }
    }
    if (b == 0 && t == 0) rowptr[n] = E;
}

// ---------------- CSR fill: consumes cnt via atomicSub (order within row is arbitrary anyway) ----------------
__global__ __launch_bounds__(256) void fill_kernel(const int* __restrict__ srcI, const int* __restrict__ dstI,
                                                   const int* __restrict__ rowptr, int* __restrict__ cnt,
                                                   int* __restrict__ col, int E) {
    int e = blockIdx.x * 256 + threadIdx.x;
    if (e < E) {
        int d = dstI[e];
        int old = atomicSub(&cnt[d], 1);
        col[rowptr[d] + old - 1] = srcI[e];
    }
}

// ---------------- weight prep: fp32 W[k][c] -> bf16, transposed [c][k], 16B-slot XOR-swizzled ----------------
// element (k,c) stored at  m*16384 + c*128 + (((k>>3) ^ (c&7))<<3) + (k&7)
__global__ __launch_bounds__(256) void wprep(const float* __restrict__ W1, const float* __restrict__ Wmu,
                                             const float* __restrict__ Wlv, unsigned short* __restrict__ out) {
    int t = blockIdx.x * 256 + threadIdx.x;    // 49152 total
    int m = t >> 14;
    int idx = t & 16383;
    const float* W = (m == 0) ? W1 : (m == 1) ? Wmu : Wlv;
    int k = idx >> 7, c = idx & 127;
    float v = W[idx];
    int dstIdx = (c << 7) | ((((k >> 3) ^ (c & 7)) << 3)) | (k & 7);
    out[(m << 14) + dstIdx] = f2bf(v);
}

// ---------------- convert: x_tilde = bf16(x * dinv[row]), 8 elems/thread ----------------
__global__ __launch_bounds__(256) void conv_scale(const float* __restrict__ X, const float* __restrict__ dinv,
                                                  uint4* __restrict__ Y, int nf8) {
    int i = blockIdx.x * 256 + threadIdx.x;
    if (i >= nf8) return;
    int row = i >> 4;                 // 16 uint4-slots per 128-elem row
    float d = dinv[row];
    const floatx4* X4 = (const floatx4*)X;
    floatx4 f0 = __builtin_nontemporal_load(&X4[i * 2]);
    floatx4 f1 = __builtin_nontemporal_load(&X4[i * 2 + 1]);
    uint4 o;
    o.x = pack2(f0.x * d, f0.y * d);
    o.y = pack2(f0.z * d, f0.w * d);
    o.z = pack2(f1.x * d, f1.y * d);
    o.w = pack2(f1.z * d, f1.w * d);
    Y[i] = o;
}

// ---------------- gather: G[j] = bf16( dinv[j] * (T[j] + sum_{s->j} T[s]) ) ----------------
// 16 nodes/block, 16 lanes/node, 8 bf16 feats (uint4) per lane. Inputs pre-scaled by dinv[src].
__global__ __launch_bounds__(256) void gather_agg(const uint4* __restrict__ T, const int* __restrict__ rowptr,
                                                  const int* __restrict__ col, const float* __restrict__ dinv,
                                                  uint4* __restrict__ G, int n) {
    int t = threadIdx.x;
    int lane16 = t & 15;
    int node = blockIdx.x * 16 + (t >> 4);
    if (node >= n) return;

    size_t ridx = (size_t)node * 16 + lane16;
    float acc[8];
    {
        uint4 v = T[ridx];  // self-loop
        acc[0] = bflo(v.x); acc[1] = bfhi(v.x); acc[2] = bflo(v.y); acc[3] = bfhi(v.y);
        acc[4] = bflo(v.z); acc[5] = bfhi(v.z); acc[6] = bflo(v.w); acc[7] = bfhi(v.w);
    }
    auto add8 = [&](uint4 v) {
        acc[0] += bflo(v.x); acc[1] += bfhi(v.x); acc[2] += bflo(v.y); acc[3] += bfhi(v.y);
        acc[4] += bflo(v.z); acc[5] += bfhi(v.z); acc[6] += bflo(v.w); acc[7] += bfhi(v.w);
    };

    int rp0 = rowptr[node], rp1 = rowptr[node + 1];
    for (int eb = rp0; eb < rp1; eb += 16) {
        int e = eb + lane16;
        int myc = (e < rp1) ? col[e] : 0;
        int m = rp1 - eb; if (m > 16) m = 16;
        int i = 0;
        for (; i + 8 <= m; i += 8) {
            int s0 = __shfl(myc, i, 16);
            int s1 = __shfl(myc, i + 1, 16);
            int s2 = __shfl(myc, i + 2, 16);
            int s3 = __shfl(myc, i + 3, 16);
            int s4 = __shfl(myc, i + 4, 16);
            int s5 = __shfl(myc, i + 5, 16);
            int s6 = __shfl(myc, i + 6, 16);
            int s7 = __shfl(myc, i + 7, 16);
            uint4 v0 = T[(size_t)s0 * 16 + lane16];
            uint4 v1 = T[(size_t)s1 * 16 + lane16];
            uint4 v2 = T[(size_t)s2 * 16 + lane16];
            uint4 v3 = T[(size_t)s3 * 16 + lane16];
            uint4 v4 = T[(size_t)s4 * 16 + lane16];
            uint4 v5 = T[(size_t)s5 * 16 + lane16];
            uint4 v6 = T[(size_t)s6 * 16 + lane16];
            uint4 v7 = T[(size_t)s7 * 16 + lane16];
            add8(v0); add8(v1); add8(v2); add8(v3);
            add8(v4); add8(v5); add8(v6); add8(v7);
        }
        for (; i + 4 <= m; i += 4) {
            int s0 = __shfl(myc, i, 16);
            int s1 = __shfl(myc, i + 1, 16);
            int s2 = __shfl(myc, i + 2, 16);
            int s3 = __shfl(myc, i + 3, 16);
            uint4 v0 = T[(size_t)s0 * 16 + lane16];
            uint4 v1 = T[(size_t)s1 * 16 + lane16];
            uint4 v2 = T[(size_t)s2 * 16 + lane16];
            uint4 v3 = T[(size_t)s3 * 16 + lane16];
            add8(v0); add8(v1); add8(v2); add8(v3);
        }
        for (; i < m; i++) {
            int s = __shfl(myc, i, 16);
            add8(T[(size_t)s * 16 + lane16]);
        }
    }

    float dj = dinv[node];
    uint4 o;
    o.x = pack2(acc[0] * dj, acc[1] * dj);
    o.y = pack2(acc[2] * dj, acc[3] * dj);
    o.z = pack2(acc[4] * dj, acc[5] * dj);
    o.w = pack2(acc[6] * dj, acc[7] * dj);
    G[ridx] = o;
}

// ---------------- MFMA GEMM single-W with epilogue ----------------
// G: n x 128 bf16 (aggregated). out = epi(G @ W + bias).  Wp: pre-swizzled bf16 [c][k].
// MODE 0: h_tilde = relu(v) * dinv[row] -> bf16.   MODE 1: recon = sigmoid(v) -> fp32 (nontemporal).
template<int MODE>
__global__ __launch_bounds__(256) void gemm_epi(const unsigned short* __restrict__ Gm,
                                                const unsigned short* __restrict__ Wp,
                                                const float* __restrict__ bias, const float* __restrict__ dinv,
                                                void* __restrict__ out, int n) {
    __shared__ __align__(16) unsigned short Wt[128 * 128];
    int t = threadIdx.x;
    {
        const uint4* g = (const uint4*)Wp;
        uint4* s = (uint4*)Wt;
        #pragma unroll
        for (int i = 0; i < 8; i++) s[i * 256 + t] = g[i * 256 + t];
    }
    __syncthreads();

    int wave = t >> 6, lane = t & 63;
    int quad = lane >> 4, mrow = lane & 15;
    int row0 = blockIdx.x * 64 + wave * 16;
    int gr = row0 + mrow; if (gr >= n) gr = n - 1;

    f32x4 acc[8];
    #pragma unroll
    for (int i = 0; i < 8; i++) acc[i] = (f32x4){0.f, 0.f, 0.f, 0.f};

    #pragma unroll
    for (int kb = 0; kb < 4; kb++) {
        int k0 = kb * 32 + quad * 8;
        union { uintx4 u4; short8 s8; } cv;
        cv.u4 = __builtin_nontemporal_load((const uintx4*)(Gm + (size_t)gr * FDIM + k0));
        short8 a = cv.s8;
        int sw = ((kb << 2) + quad) ^ (mrow & 7);
        #pragma unroll
        for (int tile = 0; tile < 8; tile++) {
            int colc = tile * 16 + mrow;
            short8 b = *(const short8*)&Wt[(colc << 7) + (sw << 3)];
            acc[tile] = __builtin_amdgcn_mfma_f32_16x16x32_bf16(a, b, acc[tile], 0, 0, 0);
        }
    }

    #pragma unroll
    for (int r = 0; r < 4; r++) {
        int rowg = row0 + quad * 4 + r;
        if (rowg >= n) continue;
        if (MODE == 0) {
            float dj = dinv[rowg];
            unsigned short* Y = (unsigned short*)out;
            #pragma unroll
            for (int tile = 0; tile < 8; tile++) {
                int c = tile * 16 + mrow;
                float v = fmaxf(acc[tile][r] + bias[c], 0.f) * dj;
                Y[(size_t)rowg * FDIM + c] = f2bf(v);
            }
        } else {
            float* Y = (float*)out;
            #pragma unroll
            for (int tile = 0; tile < 8; tile++) {
                int c = tile * 16 + mrow;
                float v = acc[tile][r] + bias[c];
                __builtin_nontemporal_store(1.f / (1.f + expf(-v)), &Y[(size_t)rowg * FDIM + c]);
            }
        }
    }
}

// ---------------- MFMA GEMM dual-W: mu, logvar, z_tilde ----------------
__global__ __launch_bounds__(256) void gemm_dual(const unsigned short* __restrict__ Gm,
                                                 const unsigned short* __restrict__ WmuP,
                                                 const unsigned short* __restrict__ WlvP,
                                                 const float* __restrict__ bmu, const float* __restrict__ blv,
                                                 const float* __restrict__ eps, const float* __restrict__ dinv,
                                                 float* __restrict__ muO, float* __restrict__ lvO,
                                                 unsigned short* __restrict__ zt, int n) {
    __shared__ __align__(16) unsigned short Wa[128 * 128];
    __shared__ __align__(16) unsigned short Wb[128 * 128];
    int t = threadIdx.x;
    {
        const uint4* g0 = (const uint4*)WmuP;
        const uint4* g1 = (const uint4*)WlvP;
        uint4* s0 = (uint4*)Wa;
        uint4* s1 = (uint4*)Wb;
        #pragma unroll
        for (int i = 0; i < 8; i++) {
            s0[i * 256 + t] = g0[i * 256 + t];
            s1[i * 256 + t] = g1[i * 256 + t];
        }
    }
    __syncthreads();

    int wave = t >> 6, lane = t & 63;
    int quad = lane >> 4, mrow = lane & 15;
    int row0 = blockIdx.x * 64 + wave * 16;
    int gr = row0 + mrow; if (gr >= n) gr = n - 1;

    f32x4 am[8], al[8];
    #pragma unroll
    for (int i = 0; i < 8; i++) { am[i] = (f32x4){0.f,0.f,0.f,0.f}; al[i] = (f32x4){0.f,0.f,0.f,0.f}; }

    #pragma unroll
    for (int kb = 0; kb < 4; kb++) {
        int k0 = kb * 32 + quad * 8;
        union { uintx4 u4; short8 s8; } cv;
        cv.u4 = __builtin_nontemporal_load((const uintx4*)(Gm + (size_t)gr * FDIM + k0));
        short8 a = cv.s8;
        int sw = ((kb << 2) + quad) ^ (mrow & 7);
        #pragma unroll
        for (int tile = 0; tile < 8; tile++) {
            int colc = tile * 16 + mrow;
            short8 b0 = *(const short8*)&Wa[(colc << 7) + (sw << 3)];
            am[tile] = __builtin_amdgcn_mfma_f32_16x16x32_bf16(a, b0, am[tile], 0, 0, 0);
            short8 b1 = *(const short8*)&Wb[(colc << 7) + (sw << 3)];
            al[tile] = __builtin_amdgcn_mfma_f32_16x16x32_bf16(a, b1, al[tile], 0, 0, 0);
        }
    }

    #pragma unroll
    for (int r = 0; r < 4; r++) {
        int rowg = row0 + quad * 4 + r;
        if (rowg >= n) continue;
        float dj = dinv[rowg];
        #pragma unroll
        for (int tile = 0; tile < 8; tile++) {
            int c = tile * 16 + mrow;
            size_t o = (size_t)rowg * FDIM + c;
            float m = am[tile][r] + bmu[c];
            float l = al[tile][r] + blv[c];
            __builtin_nontemporal_store(m, &muO[o]);
            __builtin_nontemporal_store(l, &lvO[o]);
            float ev = __builtin_nontemporal_load(&eps[o]);
            float z = ev * expf(0.5f * l) + m;
            zt[o] = f2bf(z * dj);
        }
    }
}

extern "C" void kernel_launch(void* const* d_in, const int* in_sizes, int n_in,
                              void* d_out, int out_size, void* d_ws, size_t ws_size,
                              hipStream_t stream) {
    const int F = FDIM;
    const int N = in_sizes[0] / F;
    const int E = in_sizes[1] / 2;

    const float* x   = (const float*)d_in[0];
    const int*   ei  = (const int*)d_in[1];
    const int*   srcI = ei;
    const int*   dstI = ei + E;
    const float* eps = (const float*)d_in[2];
    const float* W1  = (const float*)d_in[3];
    const float* b1  = (const float*)d_in[4];
    const float* Wmu = (const float*)d_in[5];
    const float* bmu = (const float*)d_in[6];
    const float* Wlv = (const float*)d_in[7];
    const float* blv = (const float*)d_in[8];

    float* recon = (float*)d_out;
    size_t NF = (size_t)N * F;
    float* muO = recon + NF;
    float* lvO = recon + 2 * NF;

    size_t off = 0;
    auto alloc = [&](size_t bytes) -> void* {
        void* p = (char*)d_ws + off;
        off += (bytes + 255) & ~(size_t)255;
        return p;
    };
    int*   cnt    = (int*)alloc((size_t)N * 4);
    int*   rowptr = (int*)alloc((size_t)(N + 1) * 4);
    int*   bsum   = (int*)alloc(4096);
    int*   col    = (int*)alloc((size_t)E * 4);
    float* dinv   = (float*)alloc((size_t)N * 4);
    unsigned short* WtP = (unsigned short*)alloc((size_t)3 * 16384 * 2);  // prepped W1,Wmu,Wlv
    unsigned short* bufA = (unsigned short*)alloc(NF * 2);  // scaled features (x~, h~, z~)
    unsigned short* bufB = (unsigned short*)alloc(NF * 2);  // aggregated (g1, g2, g3)

    hipMemsetAsync(cnt, 0, (size_t)N * 4, stream);

    int eb = (E + 255) / 256;
    int NB = (N + 1023) / 1024;
    deg_kernel<<<eb, 256, 0, stream>>>(dstI, cnt, E);
    scan_partial<<<NB, 256, 0, stream>>>(cnt, bsum, N);
    scan_sums<<<1, 256, 0, stream>>>(bsum, NB);
    scan_final<<<NB, 256, 0, stream>>>(cnt, bsum, rowptr, dinv, N, E);
    fill_kernel<<<eb, 256, 0, stream>>>(srcI, dstI, rowptr, cnt, col, E);
    wprep<<<192, 256, 0, stream>>>(W1, Wmu, Wlv, WtP);

    int nf8 = (int)(NF / 8);
    int cb = (nf8 + 255) / 256;
    int ab = (N + 15) / 16;
    int gb = (N + 63) / 64;

    const unsigned short* W1P  = WtP;
    const unsigned short* WmuP = WtP + 16384;
    const unsigned short* WlvP = WtP + 32768;

    // x~ = bf16(x * dinv)
    conv_scale<<<cb, 256, 0, stream>>>(x, dinv, (uint4*)bufA, nf8);
    // g1 = Agg(x~)
    gather_agg<<<ab, 256, 0, stream>>>((const uint4*)bufA, rowptr, col, dinv, (uint4*)bufB, N);
    // h~ = relu(g1 @ W1 + b1) * dinv
    gemm_epi<0><<<gb, 256, 0, stream>>>(bufB, W1P, b1, dinv, bufA, N);
    // g2 = Agg(h~)
    gather_agg<<<ab, 256, 0, stream>>>((const uint4*)bufA, rowptr, col, dinv, (uint4*)bufB, N);
    // mu, logvar, z~
    gemm_dual<<<gb, 256, 0, stream>>>(bufB, WmuP, WlvP, bmu, blv, eps, dinv, muO, lvO, bufA, N);
    // g3 = Agg(z~)
    gather_agg<<<ab, 256, 0, stream>>>((const uint4*)bufA, rowptr, col, dinv, (uint4*)bufB, N);
    // recon = sigmoid(g3 @ W1 + b1)
    gemm_epi<1><<<gb, 256, 0, stream>>>(bufB, W1P, b1, nullptr, recon, N);
}